// Round 2
// 1123.844 us; speedup vs baseline: 1.1421x; 1.1421x over previous
//
#include <hip/hip_runtime.h>
#include <math.h>

#define B_SZ 1024
#define N_SZ 100000
#define D_SZ 512
#define NBLK 3125   // N/32 row-tiles (exact: 100000 = 3125*32)

typedef __attribute__((ext_vector_type(8))) short short8;
typedef __attribute__((ext_vector_type(16))) float float16;

__device__ __forceinline__ unsigned f2bf(float x) {
    unsigned u = __float_as_uint(x);
    u += 0x7FFFu + ((u >> 16) & 1u);
    return u >> 16;                       // RNE bf16 bits in low 16
}
__device__ __forceinline__ float bf2f(unsigned h) {
    return __uint_as_float(h << 16);
}

// ---------------- PRE: split dataset to Yh/Yl, transposed Yt, norms; split X ----
__global__ __launch_bounds__(256) void pre_kernel(
    const float* __restrict__ ds, const float* __restrict__ x_t,
    short* __restrict__ Yh, short* __restrict__ Yl, short* __restrict__ Yt,
    short* __restrict__ Xh, short* __restrict__ Xl, float* __restrict__ norms)
{
    __shared__ unsigned short YS[32 * 512];   // hi tile, [n][d]
    const int bx = blockIdx.x, tid = threadIdx.x;
    if (bx < NBLK) {
        const int row = tid >> 3, seg = tid & 7;
        const size_t g = (size_t)(bx * 32 + row) * 512 + seg * 64;
        const int ls = row * 512 + seg * 64;
        float nrm = 0.f;
        #pragma unroll
        for (int i = 0; i < 16; i++) {
            float4 v = *(const float4*)(ds + g + i * 4);
            nrm += v.x*v.x + v.y*v.y + v.z*v.z + v.w*v.w;
            unsigned h0 = f2bf(v.x), h1 = f2bf(v.y), h2 = f2bf(v.z), h3 = f2bf(v.w);
            unsigned l0 = f2bf(v.x - bf2f(h0)), l1 = f2bf(v.y - bf2f(h1));
            unsigned l2 = f2bf(v.z - bf2f(h2)), l3 = f2bf(v.w - bf2f(h3));
            uint2 hw = make_uint2(h0 | (h1 << 16), h2 | (h3 << 16));
            uint2 lw = make_uint2(l0 | (l1 << 16), l2 | (l3 << 16));
            *(uint2*)(Yh + g + i * 4) = hw;
            *(uint2*)(Yl + g + i * 4) = lw;
            *(uint2*)(YS + ls + i * 4) = hw;
        }
        nrm += __shfl_xor(nrm, 1, 64);
        nrm += __shfl_xor(nrm, 2, 64);
        nrm += __shfl_xor(nrm, 4, 64);
        if ((tid & 7) == 0) norms[bx * 32 + row] = nrm;
        __syncthreads();
        // write transposed block Yt[bx][d][n']  (rows of 32 bf16 = 64 B)
        #pragma unroll
        for (int r = 0; r < 2; r++) {
            const int d = tid + r * 256;
            unsigned w[16];
            #pragma unroll
            for (int j = 0; j < 16; j++) {
                unsigned lo = YS[(2 * j) * 512 + d];
                unsigned hi = YS[(2 * j + 1) * 512 + d];
                w[j] = lo | (hi << 16);
            }
            uint4* dst = (uint4*)(Yt + (size_t)bx * 16384 + d * 32);
            dst[0] = make_uint4(w[0], w[1], w[2], w[3]);
            dst[1] = make_uint4(w[4], w[5], w[6], w[7]);
            dst[2] = make_uint4(w[8], w[9], w[10], w[11]);
            dst[3] = make_uint4(w[12], w[13], w[14], w[15]);
        }
    } else {
        const int xb = bx - NBLK;   // 0..31, X split: 1024x512 f32
        #pragma unroll
        for (int k = 0; k < 16; k++) {
            const size_t i4 = (size_t)xb * 4096 + k * 256 + tid;
            float4 v = *(const float4*)(x_t + i4 * 4);
            unsigned h0 = f2bf(v.x), h1 = f2bf(v.y), h2 = f2bf(v.z), h3 = f2bf(v.w);
            unsigned l0 = f2bf(v.x - bf2f(h0)), l1 = f2bf(v.y - bf2f(h1));
            unsigned l2 = f2bf(v.z - bf2f(h2)), l3 = f2bf(v.w - bf2f(h3));
            *(uint2*)(Xh + i4 * 4) = make_uint2(h0 | (h1 << 16), h2 | (h3 << 16));
            *(uint2*)(Xl + i4 * 4) = make_uint2(l0 | (l1 << 16), l2 | (l3 << 16));
        }
    }
}

// ---------------- MAIN: producer/consumer MFMA flash ----------------
// 512 thr = 8 waves. waves 0-3: S^T = Y.X^T (k-split 128 dims each, 3 bf16
// passes), LDS-reduce, softmax -> P-buf. waves 4-7: O^T += Yt^T.P^T for a
// 128-dim slice, pipelined one tile behind. Q-tile 64, row-tile 32.
// YhL/YlL are XOR-swizzled (T2): global source pre-swizzled so the linear
// global_load_lds write lands data at [r][c ^ ((r&7)<<3)] (shorts); reads
// apply the same XOR -> 32-way bank conflict on ds_read_b128 eliminated.
__global__ __launch_bounds__(512, 2) void attn_kernel(
    const float* __restrict__ t,
    const short* __restrict__ Xh, const short* __restrict__ Xl,
    const short* __restrict__ Yh, const short* __restrict__ Yl,
    const short* __restrict__ Yt, const float* __restrict__ norms,
    float* __restrict__ m_part, float* __restrict__ l_part,
    float* __restrict__ acc_part, int chunk)
{
    __shared__ short YhL[32 * 512];          // 32 KB
    __shared__ short YlL[32 * 512];          // 32 KB
    __shared__ float slots[4 * 64 * 33];     // S partials, pitch 33 (bank-safe b32)
    __shared__ float Pbuf[64 * 36];          // P (exp'ed), pitch 36 (16B-aligned rows)
    __shared__ float c1A[64], c2A[64], mAs[64], lAs[64], alA[64];
    __shared__ float nrmL[32];

    const int tid = threadIdx.x;
    const int wave = tid >> 6, lane = tid & 63;
    const int half = lane >> 5, l31 = lane & 31;
    const int qb = blockIdx.x * 64;
    const int s = blockIdx.y;
    const int n0s = s * chunk;
    const int n1 = min(N_SZ, n0s + chunk);
    const int numTiles = (n1 - n0s + 31) >> 5;

    if (tid < 64) {
        float tv = t[qb + tid];
        float bt = 1.0f - tv;
        float i2 = 1.0f / (2.0f * bt * bt);
        c1A[tid] = 2.0f * tv * i2;
        c2A[tid] = tv * tv * i2;
        mAs[tid] = -1e30f;
        lAs[tid] = 0.0f;
        alA[tid] = 0.0f;
    }
    __syncthreads();

    if (wave < 4) {
        // ================= PRODUCER =================
        short8 XF[2][8][2];   // [qtile][kchunk][h/l] B-frags, persistent
        #pragma unroll
        for (int qt = 0; qt < 2; qt++)
            #pragma unroll
            for (int kc = 0; kc < 8; kc++) {
                size_t off = (size_t)(qb + qt * 32 + l31) * 512 + wave * 128 + kc * 16 + half * 8;
                XF[qt][kc][0] = *(const short8*)(Xh + off);
                XF[qt][kc][1] = *(const short8*)(Xl + off);
            }

        for (int it = 0; it <= numTiles; ++it) {
            if (it < numTiles) {   // stage tile it (global src pre-swizzled)
                int n0 = n0s + it * 32;
                #pragma unroll
                for (int j = 0; j < 8; j++) {
                    int r = wave * 8 + j;
                    int gr = n0 + r;
                    if (gr < n1) {
                        const int gsw = (lane * 8) ^ ((r & 7) << 3);   // shorts
                        const short* gh = Yh + (size_t)gr * 512 + gsw;
                        const short* gl = Yl + (size_t)gr * 512 + gsw;
                        __builtin_amdgcn_global_load_lds(
                            (const __attribute__((address_space(1))) unsigned int*)gh,
                            (__attribute__((address_space(3))) unsigned int*)&YhL[r * 512], 16, 0, 0);
                        __builtin_amdgcn_global_load_lds(
                            (const __attribute__((address_space(1))) unsigned int*)gl,
                            (__attribute__((address_space(3))) unsigned int*)&YlL[r * 512], 16, 0, 0);
                    } else {
                        short8 z;
                        #pragma unroll
                        for (int e = 0; e < 8; e++) z[e] = 0;
                        *(short8*)(&YhL[r * 512 + lane * 8]) = z;
                        *(short8*)(&YlL[r * 512 + lane * 8]) = z;
                    }
                }
                if (wave == 0 && lane < 32)
                    nrmL[lane] = (n0 + lane < n1) ? norms[n0 + lane] : 1e30f;
            }
            __syncthreads();   // (a) tile staged

            if (it < numTiles) {
                float16 S0, S1;
                #pragma unroll
                for (int e = 0; e < 16; e++) { S0[e] = 0.f; S1[e] = 0.f; }
                #pragma unroll
                for (int kc = 0; kc < 8; kc++) {
                    const int koff = wave * 128 + kc * 16 + half * 8;
                    const int ksw = koff ^ ((l31 & 7) << 3);   // T2 swizzled read
                    short8 Ah = *(const short8*)(YhL + l31 * 512 + ksw);
                    short8 Al = *(const short8*)(YlL + l31 * 512 + ksw);
                    S0 = __builtin_amdgcn_mfma_f32_32x32x16_bf16(Ah, XF[0][kc][0], S0, 0, 0, 0);
                    S0 = __builtin_amdgcn_mfma_f32_32x32x16_bf16(Ah, XF[0][kc][1], S0, 0, 0, 0);
                    S0 = __builtin_amdgcn_mfma_f32_32x32x16_bf16(Al, XF[0][kc][0], S0, 0, 0, 0);
                    S1 = __builtin_amdgcn_mfma_f32_32x32x16_bf16(Ah, XF[1][kc][0], S1, 0, 0, 0);
                    S1 = __builtin_amdgcn_mfma_f32_32x32x16_bf16(Ah, XF[1][kc][1], S1, 0, 0, 0);
                    S1 = __builtin_amdgcn_mfma_f32_32x32x16_bf16(Al, XF[1][kc][0], S1, 0, 0, 0);
                }
                float* sb = &slots[wave * 2112];
                #pragma unroll
                for (int qt = 0; qt < 2; qt++) {
                    float* rowp = sb + (qt * 32 + l31) * 33;
                    #pragma unroll
                    for (int r = 0; r < 16; r++) {
                        int n = (r & 3) + 8 * (r >> 2) + 4 * half;
                        rowp[n] = qt ? S1[r] : S0[r];
                    }
                }
            }
            __syncthreads();   // (b) partials ready

            if (it < numTiles) {   // reduce + softmax -> Pbuf
                int ql = lane >> 2, nq = lane & 3;
                int q = wave * 16 + ql;
                float c1q = c1A[q], c2q = c2A[q];
                float lg[8];
                float mt = -1e30f;
                #pragma unroll
                for (int j = 0; j < 8; j++) {
                    int n = nq * 8 + j;
                    float dd = slots[q * 33 + n] + slots[2112 + q * 33 + n]
                             + slots[4224 + q * 33 + n] + slots[6336 + q * 33 + n];
                    lg[j] = c1q * dd - c2q * nrmL[n];
                    mt = fmaxf(mt, lg[j]);
                }
                mt = fmaxf(mt, __shfl_xor(mt, 1, 64));
                mt = fmaxf(mt, __shfl_xor(mt, 2, 64));
                float mo = mAs[q];
                float mn = fmaxf(mo, mt);
                float al = __expf(mo - mn);
                float ls = 0.f;
                #pragma unroll
                for (int j = 0; j < 8; j++) {
                    float p = __expf(lg[j] - mn);
                    Pbuf[q * 36 + nq * 8 + j] = p;
                    ls += p;
                }
                ls += __shfl_xor(ls, 1, 64);
                ls += __shfl_xor(ls, 2, 64);
                if (nq == 0) {
                    mAs[q] = mn;
                    lAs[q] = lAs[q] * al + ls;
                    alA[q] = al;
                }
            }
            __syncthreads();   // (c) Pbuf/alphas ready
        }
        if (tid < 64) {
            m_part[(size_t)s * B_SZ + qb + tid] = mAs[tid];
            l_part[(size_t)s * B_SZ + qb + tid] = lAs[tid];
        }
    } else {
        // ================= CONSUMER =================
        const int dbase = (wave - 4) * 128;
        float16 O[4][2];
        #pragma unroll
        for (int dt = 0; dt < 4; dt++)
            #pragma unroll
            for (int qt = 0; qt < 2; qt++)
                #pragma unroll
                for (int e = 0; e < 16; e++) O[dt][qt][e] = 0.f;

        for (int it = 0; it <= numTiles; ++it) {
            __syncthreads();   // (a)
            if (it > 0) {      // PV(it-1)
                int blk = (n0s + (it - 1) * 32) >> 5;
                const short* yb = Yt + (size_t)blk * 16384;
                float al0 = alA[l31], al1 = alA[32 + l31];
                #pragma unroll
                for (int dt = 0; dt < 4; dt++) {
                    O[dt][0] *= al0;
                    O[dt][1] *= al1;
                }
                short8 AF[4][2];
                #pragma unroll
                for (int dt = 0; dt < 4; dt++)
                    #pragma unroll
                    for (int kc = 0; kc < 2; kc++)
                        AF[dt][kc] = *(const short8*)(yb + (dbase + dt * 32 + l31) * 32 + kc * 16 + half * 8);
                short8 BF[2][2];
                #pragma unroll
                for (int qt = 0; qt < 2; qt++)
                    #pragma unroll
                    for (int kc = 0; kc < 2; kc++) {
                        const float* pr = &Pbuf[(qt * 32 + l31) * 36 + kc * 16 + half * 8];
                        float4 pa = *(const float4*)pr;
                        float4 pb = *(const float4*)(pr + 4);
                        short8 b;
                        b[0] = (short)f2bf(pa.x); b[1] = (short)f2bf(pa.y);
                        b[2] = (short)f2bf(pa.z); b[3] = (short)f2bf(pa.w);
                        b[4] = (short)f2bf(pb.x); b[5] = (short)f2bf(pb.y);
                        b[6] = (short)f2bf(pb.z); b[7] = (short)f2bf(pb.w);
                        BF[qt][kc] = b;
                    }
                #pragma unroll
                for (int dt = 0; dt < 4; dt++)
                    #pragma unroll
                    for (int qt = 0; qt < 2; qt++)
                        #pragma unroll
                        for (int kc = 0; kc < 2; kc++)
                            O[dt][qt] = __builtin_amdgcn_mfma_f32_32x32x16_bf16(
                                AF[dt][kc], BF[qt][kc], O[dt][qt], 0, 0, 0);
            }
            __syncthreads();   // (b)
            __syncthreads();   // (c)
        }
        // write O^T partials -> acc_part[s][q][d]
        #pragma unroll
        for (int dt = 0; dt < 4; dt++)
            #pragma unroll
            for (int qt = 0; qt < 2; qt++) {
                int q = qb + qt * 32 + l31;
                float* op = acc_part + ((size_t)s * B_SZ + q) * D_SZ + dbase + dt * 32 + 4 * half;
                #pragma unroll
                for (int rg = 0; rg < 4; rg++) {
                    float4 v = make_float4(O[dt][qt][4 * rg], O[dt][qt][4 * rg + 1],
                                           O[dt][qt][4 * rg + 2], O[dt][qt][4 * rg + 3]);
                    *(float4*)(op + 8 * rg) = v;
                }
            }
    }
}

// ---------------- COMBINE: merge splits + epilogue ----------------
__global__ __launch_bounds__(256) void combine_kernel(
    const float* __restrict__ x_t, const float* __restrict__ t,
    const float* __restrict__ m_part, const float* __restrict__ l_part,
    const float* __restrict__ acc_part, float* __restrict__ out, int nsplit)
{
    int q = blockIdx.x;
    int tid = threadIdx.x;
    float M = -1e30f;
    for (int s = 0; s < nsplit; s++) M = fmaxf(M, m_part[(size_t)s * B_SZ + q]);
    float L = 0.f;
    for (int s = 0; s < nsplit; s++)
        L += l_part[(size_t)s * B_SZ + q] * __expf(m_part[(size_t)s * B_SZ + q] - M);

    float tv = t[q];
    float bt = 1.0f - tv;
    float coeff = 1.0f + tv / bt;
    float invb = 1.0f / bt;
    float invL = 1.0f / L;

    int d = tid * 2;
    float2 w = make_float2(0.f, 0.f);
    for (int s = 0; s < nsplit; s++) {
        float sc = __expf(m_part[(size_t)s * B_SZ + q] - M);
        float2 av = *(const float2*)(acc_part + ((size_t)s * B_SZ + q) * D_SZ + d);
        w.x += sc * av.x; w.y += sc * av.y;
    }
    float2 xv = *(const float2*)(x_t + (size_t)q * D_SZ + d);
    float2 o;
    o.x = -invb * xv.x + coeff * w.x * invL;
    o.y = -invb * xv.y + coeff * w.y * invL;
    *(float2*)(out + (size_t)q * D_SZ + d) = o;
}

extern "C" void kernel_launch(void* const* d_in, const int* in_sizes, int n_in,
                              void* d_out, int out_size, void* d_ws, size_t ws_size,
                              hipStream_t stream) {
    const float* x_t = (const float*)d_in[0];
    const float* t   = (const float*)d_in[1];
    const float* ds  = (const float*)d_in[2];
    float* out = (float*)d_out;

    short* wsS = (short*)d_ws;
    short* Yh = wsS;                              // 51,200,000 shorts
    short* Yl = wsS + 51200000;
    short* Yt = wsS + 102400000;
    short* Xh = wsS + 153600000;                  // 524,288 shorts
    short* Xl = wsS + 154124288;
    float* fbase = (float*)((char*)d_ws + 309297152);   // 16B-aligned
    float* norms = fbase;                         // 100,000 f32 (400,000 B)
    int nsplit = 16;
    while (nsplit > 1 &&
           309697152ULL + (size_t)nsplit * 1024 * 4 * (2 + 512) > ws_size)
        nsplit >>= 1;
    float* m_part = fbase + 100000;
    float* l_part = m_part + (size_t)nsplit * B_SZ;
    float* acc    = l_part + (size_t)nsplit * B_SZ;
    int chunk = 32 * ((N_SZ + 32 * nsplit - 1) / (32 * nsplit));

    pre_kernel<<<dim3(NBLK + 32), dim3(256), 0, stream>>>(ds, x_t, Yh, Yl, Yt, Xh, Xl, norms);
    attn_kernel<<<dim3(16, nsplit), dim3(512), 0, stream>>>(
        t, Xh, Xl, Yh, Yl, Yt, norms, m_part, l_part, acc, chunk);
    combine_kernel<<<dim3(B_SZ), dim3(256), 0, stream>>>(
        x_t, t, m_part, l_part, acc, out, nsplit);
}

// Round 3
// 1116.782 us; speedup vs baseline: 1.1493x; 1.0063x over previous
//
#include <hip/hip_runtime.h>
#include <math.h>

#define B_SZ 1024
#define N_SZ 100000
#define D_SZ 512
#define NBLK 3125   // N/32 row-tiles (exact: 100000 = 3125*32)

typedef __attribute__((ext_vector_type(8))) short short8;
typedef __attribute__((ext_vector_type(16))) float float16;

__device__ __forceinline__ unsigned f2bf(float x) {
    unsigned u = __float_as_uint(x);
    u += 0x7FFFu + ((u >> 16) & 1u);
    return u >> 16;                       // RNE bf16 bits in low 16
}
__device__ __forceinline__ float bf2f(unsigned h) {
    return __uint_as_float(h << 16);
}

// ---------------- PRE: split dataset to Yh/Yl, transposed Yt, norms; split X ----
__global__ __launch_bounds__(256) void pre_kernel(
    const float* __restrict__ ds, const float* __restrict__ x_t,
    short* __restrict__ Yh, short* __restrict__ Yl, short* __restrict__ Yt,
    short* __restrict__ Xh, short* __restrict__ Xl, float* __restrict__ norms)
{
    __shared__ unsigned short YS[32 * 512];   // hi tile, [n][d]
    const int bx = blockIdx.x, tid = threadIdx.x;
    if (bx < NBLK) {
        const int row = tid >> 3, seg = tid & 7;
        const size_t g = (size_t)(bx * 32 + row) * 512 + seg * 64;
        const int ls = row * 512 + seg * 64;
        float nrm = 0.f;
        #pragma unroll
        for (int i = 0; i < 16; i++) {
            float4 v = *(const float4*)(ds + g + i * 4);
            nrm += v.x*v.x + v.y*v.y + v.z*v.z + v.w*v.w;
            unsigned h0 = f2bf(v.x), h1 = f2bf(v.y), h2 = f2bf(v.z), h3 = f2bf(v.w);
            unsigned l0 = f2bf(v.x - bf2f(h0)), l1 = f2bf(v.y - bf2f(h1));
            unsigned l2 = f2bf(v.z - bf2f(h2)), l3 = f2bf(v.w - bf2f(h3));
            uint2 hw = make_uint2(h0 | (h1 << 16), h2 | (h3 << 16));
            uint2 lw = make_uint2(l0 | (l1 << 16), l2 | (l3 << 16));
            *(uint2*)(Yh + g + i * 4) = hw;
            *(uint2*)(Yl + g + i * 4) = lw;
            *(uint2*)(YS + ls + i * 4) = hw;
        }
        nrm += __shfl_xor(nrm, 1, 64);
        nrm += __shfl_xor(nrm, 2, 64);
        nrm += __shfl_xor(nrm, 4, 64);
        if ((tid & 7) == 0) norms[bx * 32 + row] = nrm;
        __syncthreads();
        // write transposed block Yt[bx][d][n']  (rows of 32 bf16 = 64 B)
        #pragma unroll
        for (int r = 0; r < 2; r++) {
            const int d = tid + r * 256;
            unsigned w[16];
            #pragma unroll
            for (int j = 0; j < 16; j++) {
                unsigned lo = YS[(2 * j) * 512 + d];
                unsigned hi = YS[(2 * j + 1) * 512 + d];
                w[j] = lo | (hi << 16);
            }
            uint4* dst = (uint4*)(Yt + (size_t)bx * 16384 + d * 32);
            dst[0] = make_uint4(w[0], w[1], w[2], w[3]);
            dst[1] = make_uint4(w[4], w[5], w[6], w[7]);
            dst[2] = make_uint4(w[8], w[9], w[10], w[11]);
            dst[3] = make_uint4(w[12], w[13], w[14], w[15]);
        }
    } else {
        const int xb = bx - NBLK;   // 0..31, X split: 1024x512 f32
        #pragma unroll
        for (int k = 0; k < 16; k++) {
            const size_t i4 = (size_t)xb * 4096 + k * 256 + tid;
            float4 v = *(const float4*)(x_t + i4 * 4);
            unsigned h0 = f2bf(v.x), h1 = f2bf(v.y), h2 = f2bf(v.z), h3 = f2bf(v.w);
            unsigned l0 = f2bf(v.x - bf2f(h0)), l1 = f2bf(v.y - bf2f(h1));
            unsigned l2 = f2bf(v.z - bf2f(h2)), l3 = f2bf(v.w - bf2f(h3));
            *(uint2*)(Xh + i4 * 4) = make_uint2(h0 | (h1 << 16), h2 | (h3 << 16));
            *(uint2*)(Xl + i4 * 4) = make_uint2(l0 | (l1 << 16), l2 | (l3 << 16));
        }
    }
}

// ---------------- MAIN: producer/consumer MFMA flash ----------------
// 512 thr = 8 waves. waves 0-3: S^T = Y.X^T (k-split 128 dims each, 3 bf16
// passes), LDS-reduce, softmax -> P-buf. waves 4-7: O^T += Yt^T.P^T for a
// 128-dim slice, pipelined one tile behind. Q-tile 64, row-tile 32.
// YhL/YlL are XOR-swizzled (T2). Block remap (T1 chunk-locality): all 16
// q-blocks sharing an s-chunk land on ONE XCD (fid%8 heuristic) so each
// Y-tile is fetched into exactly one L2 and broadcast to its 16 sharers.
__global__ __launch_bounds__(512, 2) void attn_kernel(
    const float* __restrict__ t,
    const short* __restrict__ Xh, const short* __restrict__ Xl,
    const short* __restrict__ Yh, const short* __restrict__ Yl,
    const short* __restrict__ Yt, const float* __restrict__ norms,
    float* __restrict__ m_part, float* __restrict__ l_part,
    float* __restrict__ acc_part, int chunk)
{
    __shared__ short YhL[32 * 512];          // 32 KB
    __shared__ short YlL[32 * 512];          // 32 KB
    __shared__ float slots[4 * 64 * 33];     // S partials, pitch 33 (bank-safe b32)
    __shared__ float Pbuf[64 * 36];          // P (exp'ed), pitch 36 (16B-aligned rows)
    __shared__ float c1A[64], c2A[64], mAs[64], lAs[64], alA[64];
    __shared__ float nrmL[32];

    const int tid = threadIdx.x;
    const int wave = tid >> 6, lane = tid & 63;
    const int half = lane >> 5, l31 = lane & 31;

    // --- T1 chunk->XCD co-location remap (bijective; neutral if heuristic off)
    int qbi = blockIdx.x, si = blockIdx.y;
    if (gridDim.x == 16 && gridDim.y == 16) {
        int fid = blockIdx.x + (blockIdx.y << 4);
        int xcd = fid & 7, slot = fid >> 3;
        si = xcd + ((slot & 1) << 3);   // all 16 blocks of chunk si share fid%8
        qbi = slot >> 1;
    }
    const int qb = qbi * 64;
    const int s = si;
    const int n0s = s * chunk;
    const int n1 = min(N_SZ, n0s + chunk);
    const int numTiles = (n1 - n0s + 31) >> 5;

    if (tid < 64) {
        float tv = t[qb + tid];
        float bt = 1.0f - tv;
        float i2 = 1.0f / (2.0f * bt * bt);
        c1A[tid] = 2.0f * tv * i2;
        c2A[tid] = tv * tv * i2;
        mAs[tid] = -1e30f;
        lAs[tid] = 0.0f;
        alA[tid] = 0.0f;
    }
    __syncthreads();

    if (wave < 4) {
        // ================= PRODUCER =================
        short8 XF[2][8][2];   // [qtile][kchunk][h/l] B-frags, persistent
        #pragma unroll
        for (int qt = 0; qt < 2; qt++)
            #pragma unroll
            for (int kc = 0; kc < 8; kc++) {
                size_t off = (size_t)(qb + qt * 32 + l31) * 512 + wave * 128 + kc * 16 + half * 8;
                XF[qt][kc][0] = *(const short8*)(Xh + off);
                XF[qt][kc][1] = *(const short8*)(Xl + off);
            }

        for (int it = 0; it <= numTiles; ++it) {
            if (it < numTiles) {   // stage tile it (global src pre-swizzled)
                int n0 = n0s + it * 32;
                #pragma unroll
                for (int j = 0; j < 8; j++) {
                    int r = wave * 8 + j;
                    int gr = n0 + r;
                    if (gr < n1) {
                        const int gsw = (lane * 8) ^ ((r & 7) << 3);   // shorts
                        const short* gh = Yh + (size_t)gr * 512 + gsw;
                        const short* gl = Yl + (size_t)gr * 512 + gsw;
                        __builtin_amdgcn_global_load_lds(
                            (const __attribute__((address_space(1))) unsigned int*)gh,
                            (__attribute__((address_space(3))) unsigned int*)&YhL[r * 512], 16, 0, 0);
                        __builtin_amdgcn_global_load_lds(
                            (const __attribute__((address_space(1))) unsigned int*)gl,
                            (__attribute__((address_space(3))) unsigned int*)&YlL[r * 512], 16, 0, 0);
                    } else {
                        short8 z;
                        #pragma unroll
                        for (int e = 0; e < 8; e++) z[e] = 0;
                        *(short8*)(&YhL[r * 512 + lane * 8]) = z;
                        *(short8*)(&YlL[r * 512 + lane * 8]) = z;
                    }
                }
                if (wave == 0 && lane < 32)
                    nrmL[lane] = (n0 + lane < n1) ? norms[n0 + lane] : 1e30f;
            }
            __syncthreads();   // (a) tile staged

            if (it < numTiles) {
                float16 S0, S1;
                #pragma unroll
                for (int e = 0; e < 16; e++) { S0[e] = 0.f; S1[e] = 0.f; }
                #pragma unroll
                for (int kc = 0; kc < 8; kc++) {
                    const int koff = wave * 128 + kc * 16 + half * 8;
                    const int ksw = koff ^ ((l31 & 7) << 3);   // T2 swizzled read
                    short8 Ah = *(const short8*)(YhL + l31 * 512 + ksw);
                    short8 Al = *(const short8*)(YlL + l31 * 512 + ksw);
                    S0 = __builtin_amdgcn_mfma_f32_32x32x16_bf16(Ah, XF[0][kc][0], S0, 0, 0, 0);
                    S0 = __builtin_amdgcn_mfma_f32_32x32x16_bf16(Ah, XF[0][kc][1], S0, 0, 0, 0);
                    S0 = __builtin_amdgcn_mfma_f32_32x32x16_bf16(Al, XF[0][kc][0], S0, 0, 0, 0);
                    S1 = __builtin_amdgcn_mfma_f32_32x32x16_bf16(Ah, XF[1][kc][0], S1, 0, 0, 0);
                    S1 = __builtin_amdgcn_mfma_f32_32x32x16_bf16(Ah, XF[1][kc][1], S1, 0, 0, 0);
                    S1 = __builtin_amdgcn_mfma_f32_32x32x16_bf16(Al, XF[1][kc][0], S1, 0, 0, 0);
                }
                float* sb = &slots[wave * 2112];
                #pragma unroll
                for (int qt = 0; qt < 2; qt++) {
                    float* rowp = sb + (qt * 32 + l31) * 33;
                    #pragma unroll
                    for (int r = 0; r < 16; r++) {
                        int n = (r & 3) + 8 * (r >> 2) + 4 * half;
                        rowp[n] = qt ? S1[r] : S0[r];
                    }
                }
            }
            __syncthreads();   // (b) partials ready

            if (it < numTiles) {   // reduce + softmax -> Pbuf
                int ql = lane >> 2, nq = lane & 3;
                int q = wave * 16 + ql;
                float c1q = c1A[q], c2q = c2A[q];
                float lg[8];
                float mt = -1e30f;
                #pragma unroll
                for (int j = 0; j < 8; j++) {
                    int n = nq * 8 + j;
                    float dd = slots[q * 33 + n] + slots[2112 + q * 33 + n]
                             + slots[4224 + q * 33 + n] + slots[6336 + q * 33 + n];
                    lg[j] = c1q * dd - c2q * nrmL[n];
                    mt = fmaxf(mt, lg[j]);
                }
                mt = fmaxf(mt, __shfl_xor(mt, 1, 64));
                mt = fmaxf(mt, __shfl_xor(mt, 2, 64));
                float mo = mAs[q];
                float mn = fmaxf(mo, mt);
                float al = __expf(mo - mn);
                float ls = 0.f;
                #pragma unroll
                for (int j = 0; j < 8; j++) {
                    float p = __expf(lg[j] - mn);
                    Pbuf[q * 36 + nq * 8 + j] = p;
                    ls += p;
                }
                ls += __shfl_xor(ls, 1, 64);
                ls += __shfl_xor(ls, 2, 64);
                if (nq == 0) {
                    mAs[q] = mn;
                    lAs[q] = lAs[q] * al + ls;
                    alA[q] = al;
                }
            }
            __syncthreads();   // (c) Pbuf/alphas ready
        }
        if (tid < 64) {
            m_part[(size_t)s * B_SZ + qb + tid] = mAs[tid];
            l_part[(size_t)s * B_SZ + qb + tid] = lAs[tid];
        }
    } else {
        // ================= CONSUMER =================
        const int dbase = (wave - 4) * 128;
        float16 O[4][2];
        #pragma unroll
        for (int dt = 0; dt < 4; dt++)
            #pragma unroll
            for (int qt = 0; qt < 2; qt++)
                #pragma unroll
                for (int e = 0; e < 16; e++) O[dt][qt][e] = 0.f;

        for (int it = 0; it <= numTiles; ++it) {
            __syncthreads();   // (a)
            if (it > 0) {      // PV(it-1)
                int blk = (n0s + (it - 1) * 32) >> 5;
                const short* yb = Yt + (size_t)blk * 16384;
                float al0 = alA[l31], al1 = alA[32 + l31];
                #pragma unroll
                for (int dt = 0; dt < 4; dt++) {
                    O[dt][0] *= al0;
                    O[dt][1] *= al1;
                }
                short8 AF[4][2];
                #pragma unroll
                for (int dt = 0; dt < 4; dt++)
                    #pragma unroll
                    for (int kc = 0; kc < 2; kc++)
                        AF[dt][kc] = *(const short8*)(yb + (dbase + dt * 32 + l31) * 32 + kc * 16 + half * 8);
                short8 BF[2][2];
                #pragma unroll
                for (int qt = 0; qt < 2; qt++)
                    #pragma unroll
                    for (int kc = 0; kc < 2; kc++) {
                        const float* pr = &Pbuf[(qt * 32 + l31) * 36 + kc * 16 + half * 8];
                        float4 pa = *(const float4*)pr;
                        float4 pb = *(const float4*)(pr + 4);
                        short8 b;
                        b[0] = (short)f2bf(pa.x); b[1] = (short)f2bf(pa.y);
                        b[2] = (short)f2bf(pa.z); b[3] = (short)f2bf(pa.w);
                        b[4] = (short)f2bf(pb.x); b[5] = (short)f2bf(pb.y);
                        b[6] = (short)f2bf(pb.z); b[7] = (short)f2bf(pb.w);
                        BF[qt][kc] = b;
                    }
                #pragma unroll
                for (int dt = 0; dt < 4; dt++)
                    #pragma unroll
                    for (int qt = 0; qt < 2; qt++)
                        #pragma unroll
                        for (int kc = 0; kc < 2; kc++)
                            O[dt][qt] = __builtin_amdgcn_mfma_f32_32x32x16_bf16(
                                AF[dt][kc], BF[qt][kc], O[dt][qt], 0, 0, 0);
            }
            __syncthreads();   // (b)
            __syncthreads();   // (c)
        }
        // write O^T partials -> acc_part[s][q][d]
        #pragma unroll
        for (int dt = 0; dt < 4; dt++)
            #pragma unroll
            for (int qt = 0; qt < 2; qt++) {
                int q = qb + qt * 32 + l31;
                float* op = acc_part + ((size_t)s * B_SZ + q) * D_SZ + dbase + dt * 32 + 4 * half;
                #pragma unroll
                for (int rg = 0; rg < 4; rg++) {
                    float4 v = make_float4(O[dt][qt][4 * rg], O[dt][qt][4 * rg + 1],
                                           O[dt][qt][4 * rg + 2], O[dt][qt][4 * rg + 3]);
                    *(float4*)(op + 8 * rg) = v;
                }
            }
    }
}

// ---------------- COMBINE: merge splits + epilogue ----------------
__global__ __launch_bounds__(256) void combine_kernel(
    const float* __restrict__ x_t, const float* __restrict__ t,
    const float* __restrict__ m_part, const float* __restrict__ l_part,
    const float* __restrict__ acc_part, float* __restrict__ out, int nsplit)
{
    int q = blockIdx.x;
    int tid = threadIdx.x;
    float M = -1e30f;
    for (int s = 0; s < nsplit; s++) M = fmaxf(M, m_part[(size_t)s * B_SZ + q]);
    float L = 0.f;
    for (int s = 0; s < nsplit; s++)
        L += l_part[(size_t)s * B_SZ + q] * __expf(m_part[(size_t)s * B_SZ + q] - M);

    float tv = t[q];
    float bt = 1.0f - tv;
    float coeff = 1.0f + tv / bt;
    float invb = 1.0f / bt;
    float invL = 1.0f / L;

    int d = tid * 2;
    float2 w = make_float2(0.f, 0.f);
    for (int s = 0; s < nsplit; s++) {
        float sc = __expf(m_part[(size_t)s * B_SZ + q] - M);
        float2 av = *(const float2*)(acc_part + ((size_t)s * B_SZ + q) * D_SZ + d);
        w.x += sc * av.x; w.y += sc * av.y;
    }
    float2 xv = *(const float2*)(x_t + (size_t)q * D_SZ + d);
    float2 o;
    o.x = -invb * xv.x + coeff * w.x * invL;
    o.y = -invb * xv.y + coeff * w.y * invL;
    *(float2*)(out + (size_t)q * D_SZ + d) = o;
}

extern "C" void kernel_launch(void* const* d_in, const int* in_sizes, int n_in,
                              void* d_out, int out_size, void* d_ws, size_t ws_size,
                              hipStream_t stream) {
    const float* x_t = (const float*)d_in[0];
    const float* t   = (const float*)d_in[1];
    const float* ds  = (const float*)d_in[2];
    float* out = (float*)d_out;

    short* wsS = (short*)d_ws;
    short* Yh = wsS;                              // 51,200,000 shorts
    short* Yl = wsS + 51200000;
    short* Yt = wsS + 102400000;
    short* Xh = wsS + 153600000;                  // 524,288 shorts
    short* Xl = wsS + 154124288;
    float* fbase = (float*)((char*)d_ws + 309297152);   // 16B-aligned
    float* norms = fbase;                         // 100,000 f32 (400,000 B)
    int nsplit = 16;
    while (nsplit > 1 &&
           309697152ULL + (size_t)nsplit * 1024 * 4 * (2 + 512) > ws_size)
        nsplit >>= 1;
    float* m_part = fbase + 100000;
    float* l_part = m_part + (size_t)nsplit * B_SZ;
    float* acc    = l_part + (size_t)nsplit * B_SZ;
    int chunk = 32 * ((N_SZ + 32 * nsplit - 1) / (32 * nsplit));

    pre_kernel<<<dim3(NBLK + 32), dim3(256), 0, stream>>>(ds, x_t, Yh, Yl, Yt, Xh, Xl, norms);
    attn_kernel<<<dim3(16, nsplit), dim3(512), 0, stream>>>(
        t, Xh, Xl, Yh, Yl, Yt, norms, m_part, l_part, acc, chunk);
    combine_kernel<<<dim3(B_SZ), dim3(256), 0, stream>>>(
        x_t, t, m_part, l_part, acc, out, nsplit);
}